// Round 13
// baseline (163.394 us; speedup 1.0000x reference)
//
#include <hip/hip_runtime.h>
#include <hip/hip_bf16.h>
#include <stdint.h>

#define KDIM 4096
#define NDIM 4096
#define MDIM 4096
#define BM 256
#define BN 256
#define BK 64

typedef __attribute__((ext_vector_type(8))) short bf16x8;
typedef __attribute__((ext_vector_type(4))) float f32x4;

// ---------- helpers ----------

__device__ __forceinline__ unsigned short bf16bits(float f) {
    union { float f; uint32_t u; } c; c.f = f;
    uint32_t u = c.u;
    uint32_t r = (u + 0x7fffu + ((u >> 16) & 1u)) >> 16;   // RNE
    return (unsigned short)r;
}

// Faithful FP4 E2M1 quant-dequant (matches reference float math).
__device__ __forceinline__ float fp4qd(float x) {
    float a = fabsf(x);
    if (a == 0.0f) return 0.0f;
    float e = floorf(log2f(a));
    float val;
    if (e < 0.0f) {                       // subnormal path
        float mant = fminf(fmaxf(rintf(a * 2.0f), 0.0f), 1.0f);
        val = mant * 0.5f;
    } else {
        float ec = fminf(e, 2.0f);
        float p  = exp2f(ec);             // exact: 1,2,4
        float mant = fminf(fmaxf(rintf((a / p - 1.0f) * 2.0f), 0.0f), 1.0f);
        val = (1.0f + 0.5f * mant) * p;
    }
    return (x < 0.0f) ? -val : val;
}

__device__ __forceinline__ void gld16(void* lds, const void* g) {
    __builtin_amdgcn_global_load_lds(
        (const __attribute__((address_space(1))) unsigned int*)g,
        (__attribute__((address_space(3))) unsigned int*)lds,
        16, 0, 0);
}

// ---------- fused prep (R9-verified) ----------
// blocks [0,16384): x f32->bf16 (linear).
// blocks [16384,18432): W fp4-qd -> bf16 in FRAGMENT-MAJOR layout:
//   Wq2[kt][c][inst][lane][16B]  (inst stride 1KB, c 8KB, kt 512KB)
//   inst = nf + ks*4; lane = (row&15) | (kslot<<4);
//   granule holds B[row][kt*64+ks*32+kslot*8 .. +8], row = c*64+nf*16+(row&15).
__global__ __launch_bounds__(256) void prep_kernel(const float* __restrict__ X,
                                                   const float* __restrict__ W,
                                                   unsigned short* __restrict__ Xb,
                                                   char* __restrict__ Wq2) {
    int bid = blockIdx.x;
    int tid = threadIdx.x;
    if (bid < 16384) {
        size_t i = ((size_t)bid * 256 + tid) * 4;
        float4 v = *(const float4*)(X + i);
        ushort4 o;
        o.x = bf16bits(v.x); o.y = bf16bits(v.y);
        o.z = bf16bits(v.z); o.w = bf16bits(v.w);
        *(ushort4*)(Xb + i) = o;
    } else {
        int bw = bid - 16384;            // [0, 2048)
        int rb = bw >> 3;                // row-block (16 rows)
        int kb = bw & 7;                 // k-block (512 k)
        int row = rb * 16 + (tid >> 4);
        int kq  = tid & 15;
        int k0  = kb * 512 + kq * 32;
        const float* src = W + (size_t)row * KDIM + k0;

        float v[32];
        float am = 0.f;
        #pragma unroll
        for (int j = 0; j < 8; ++j) {
            float4 f = *(const float4*)(src + j * 4);
            v[j*4+0] = f.x; v[j*4+1] = f.y; v[j*4+2] = f.z; v[j*4+3] = f.w;
            am = fmaxf(am, fmaxf(fmaxf(fabsf(f.x), fabsf(f.y)),
                                 fmaxf(fabsf(f.z), fabsf(f.w))));
        }
        am = fmaxf(am, __shfl_xor(am, 1));
        am = fmaxf(am, __shfl_xor(am, 2));          // quad (t&3) = one 128-group
        float scale = (am == 0.0f) ? 1.0f : am / 6.0f;

        const int c   = row >> 6;
        const int nf  = (row >> 4) & 3;
        const int r15 = row & 15;
        #pragma unroll
        for (int g = 0; g < 4; ++g) {
            uint32_t u[4];
            #pragma unroll
            for (int p = 0; p < 4; ++p) {
                float q0 = fp4qd(v[g*8 + p*2    ] / scale) * scale;
                float q1 = fp4qd(v[g*8 + p*2 + 1] / scale) * scale;
                u[p] = (uint32_t)bf16bits(q0) | ((uint32_t)bf16bits(q1) << 16);
            }
            int k8    = (k0 >> 3) + g;
            int kt    = k8 >> 3;
            int kk8   = k8 & 7;
            int ks    = kk8 >> 2;
            int kslot = kk8 & 3;
            size_t addr = ((size_t)((kt * 64 + c) * 8 + nf + ks * 4) << 10)
                        + (size_t)((kslot * 16 + r15) << 4);
            uint4 o = make_uint4(u[0], u[1], u[2], u[3]);
            *(uint4*)(Wq2 + addr) = o;
        }
    }
}

// ---------- GEMM: 256x256 tile, A in 4-buffer LDS rotation, B in regs -----
// C = A @ B^T + bias. 8 waves (2M x 4N), per-wave 128x64, acc[8][4].
// LDS = A only, 4 bufs x 32KB = 128KB; buf(t) = t & 3.
// FULL-BUFFER ledger (R12's bug fixed: RD_A(b,mh) reads BOTH stage-halves
// because wm=1 waves' rows live in h1): buf for tile t is staged entirely
// during tile t-2 (alpha: h0, beta: h1) -> read 2 K-tiles (4 phases) later.
// VM(20) at each beta-end: ops younger than the target stages =
// betaPrev.B(8)+alpha.s(2)+beta.s(2)+beta.B(8) = 20 -> in-order vmcnt drains
// exactly the buffer read next alpha, ~2000cy slack (wait usually free).
// B: fragment-major Wq2, 8 x 1KB coalesced dwordx4 -> regs (bE/bO, period 2,
// reloaded at beta for tile t+2; reg-RAW compiler-guarded).
// LDS traffic/K-tile: A reads 128KB + writes 32KB (~1880cy) < MFMA 2483cy.

#define BAR()    __builtin_amdgcn_s_barrier()
#define LGKM0()  asm volatile("s_waitcnt lgkmcnt(0)" ::: "memory")
#define VM20()   asm volatile("s_waitcnt vmcnt(20)" ::: "memory")
#define VM0()    asm volatile("s_waitcnt vmcnt(0)" ::: "memory")
#define SCH0()   __builtin_amdgcn_sched_barrier(0)
#define PRIO(x)  __builtin_amdgcn_s_setprio(x)

__global__ __launch_bounds__(512, 2) void gemm256(const unsigned short* __restrict__ A,
                                                  const char* __restrict__ Bq,
                                                  const float* __restrict__ bias,
                                                  float* __restrict__ C) {
    __shared__ __attribute__((aligned(16))) char smem[4][32768];  // [buf][A-tile]
    char* sm = (char*)&smem[0][0];

    const int t = threadIdx.x;
    const int l = t & 63;
    const int w = __builtin_amdgcn_readfirstlane(t >> 6);  // 0..7
    const int wm = w >> 2;        // 0..1  (M half)
    const int wn = w & 3;         // 0..3  (N quarter)

    // bijective XCD swizzle (256 blocks, 8 XCDs)
    int bid = blockIdx.x;
    int swz = (bid & 7) * 32 + (bid >> 3);
    int brow = (swz >> 4) * BM;
    int bcol = (swz & 15) * BN;

    // ---- A staging (pre-swizzled global source, linear LDS dest) ----
    const int lr8  = l >> 3;
    const int slot = l & 7;
    const int scol = (slot ^ lr8) << 3;
    const unsigned short* pA = A + (size_t)(brow + w * 8 + lr8) * KDIM + scol;

    // stage one 128-row half of A(kt) into buffer b (2 gld16)
#define S_A(b, h, kt) do {                                                     \
    const unsigned short* _s = pA + (size_t)(h) * 128 * KDIM + (size_t)(kt) * BK; \
    gld16(sm + (b) * 32768 + (h) * 16384 + w * 1024, _s);                      \
    gld16(sm + (b) * 32768 + (h) * 16384 + 8192 + w * 1024,                    \
          _s + (size_t)64 * KDIM);                                             \
} while (0)

    // ---- A fragment reads (16x16x32) ----
    const int fr  = l & 15;
    const int fq  = l >> 4;
    const int kx0 = ((fq    ) ^ (fr & 7)) << 4;
    const int kx1 = ((fq + 4) ^ (fr & 7)) << 4;
    const int frA = fr * 128;

#define RD_A(b, mh) do {                                                        \
    const char* _p = sm + (b) * 32768 + wm * 16384 + (mh) * 8192 + frA;         \
    _Pragma("unroll")                                                           \
    for (int m = 0; m < 4; ++m) {                                               \
        av[m][0] = *(const bf16x8*)(_p + m * 2048 + kx0);                       \
        av[m][1] = *(const bf16x8*)(_p + m * 2048 + kx1);                       \
    }                                                                           \
} while (0)

    // ---- B fragment loads: fragment-major, 8 x 1KB contiguous / K-tile ----
    const char* pBq = Bq + ((size_t)(bcol >> 6) + wn) * 8192 + (size_t)l * 16;

#define GLB_B(arr, kt) do {                                                     \
    const char* _b = pBq + (size_t)(kt) * 524288;                               \
    arr[0][0] = *(const bf16x8*)(_b       );                                    \
    arr[1][0] = *(const bf16x8*)(_b + 1024);                                    \
    arr[2][0] = *(const bf16x8*)(_b + 2048);                                    \
    arr[3][0] = *(const bf16x8*)(_b + 3072);                                    \
    arr[0][1] = *(const bf16x8*)(_b + 4096);                                    \
    arr[1][1] = *(const bf16x8*)(_b + 5120);                                    \
    arr[2][1] = *(const bf16x8*)(_b + 6144);                                    \
    arr[3][1] = *(const bf16x8*)(_b + 7168);                                    \
} while (0)

    // one mh-half of the per-wave output: 4m x 4nf x 2ks = 32 MFMA (ks-outer)
#define MMH(mh, B_)                                                             \
    _Pragma("unroll")                                                           \
    for (int ks = 0; ks < 2; ++ks)                                              \
        _Pragma("unroll")                                                       \
        for (int m = 0; m < 4; ++m)                                             \
            _Pragma("unroll")                                                   \
            for (int nf = 0; nf < 4; ++nf)                                      \
                acc[(mh) * 4 + m][nf] =                                         \
                    __builtin_amdgcn_mfma_f32_16x16x32_bf16(                    \
                        av[m][ks], B_[nf][ks], acc[(mh) * 4 + m][nf], 0, 0, 0);

    f32x4 acc[8][4];
    #pragma unroll
    for (int m = 0; m < 8; ++m)
        #pragma unroll
        for (int n = 0; n < 4; ++n)
            acc[m][n] = f32x4{0.f, 0.f, 0.f, 0.f};

    bf16x8 av[4][2], bE[4][2], bO[4][2];

    // ---- prologue: tiles 0,1 -> bufs 0,1 (full); B tiles 0,1 -> bE,bO ----
    S_A(0, 0, 0); S_A(0, 1, 0); S_A(1, 0, 1); S_A(1, 1, 1);
    GLB_B(bE, 0); GLB_B(bO, 1);
    VM0();
    BAR(); SCH0();

    // one K-tile: buf j, B-reg BREG, stages tile (4it+j+2) into buf (j+2)&3
#define TILE_K(j, BREG, kidx) do {                                              \
    /* alpha: read (j, mh0); stage h0 of tile+2 */                              \
    RD_A(j, 0); S_A((j + 2) & 3, 0, kidx);                                      \
    BAR(); LGKM0(); SCH0();                                                     \
    PRIO(1); MMH(0, BREG); PRIO(0);                                            \
    /* beta: read (j, mh1); stage h1 of tile+2 ; reload BREG(tile+2) */         \
    RD_A(j, 1); S_A((j + 2) & 3, 1, kidx);                                      \
    BAR(); LGKM0(); SCH0();                                                     \
    PRIO(1); MMH(1, BREG); PRIO(0);                                            \
    GLB_B(BREG, kidx);                                                          \
    VM20();                                                                     \
} while (0)

    // ---- main loop: 4 K-tiles / iteration (bufs 0..3), 16 iterations ----
    for (int it = 0; it < 16; ++it) {
        const int kt2 = (4 * it + 2) & 63;
        const int kt3 = (4 * it + 3) & 63;
        const int kt4 = (4 * it + 4) & 63;   // wraps on last iter (never read)
        const int kt5 = (4 * it + 5) & 63;   // wraps on last iter (never read)
        TILE_K(0, bE, kt2);
        TILE_K(1, bO, kt3);
        TILE_K(2, bE, kt4);
        TILE_K(3, bO, kt5);
    }

    // ---- epilogue: C[row][col] = acc + bias[col] ----
    // C/D layout: col = lane&15, row = (lane>>4)*4 + reg
    float bb[4];
    #pragma unroll
    for (int n = 0; n < 4; ++n) bb[n] = bias[bcol + wn * 64 + n * 16 + fr];
    #pragma unroll
    for (int mi = 0; mi < 8; ++mi) {
        #pragma unroll
        for (int q = 0; q < 4; ++q) {
            int row = brow + wm * 128 + mi * 16 + fq * 4 + q;
            float* crow = C + (size_t)row * NDIM + bcol + wn * 64;
            #pragma unroll
            for (int n = 0; n < 4; ++n)
                crow[n * 16 + fr] = acc[mi][n][q] + bb[n];
        }
    }
}

// ---------- launch ----------
extern "C" void kernel_launch(void* const* d_in, const int* in_sizes, int n_in,
                              void* d_out, int out_size, void* d_ws, size_t ws_size,
                              hipStream_t stream) {
    const float* x = (const float*)d_in[0];
    const float* w = (const float*)d_in[1];
    const float* b = (const float*)d_in[2];
    float* out = (float*)d_out;

    unsigned short* xb = (unsigned short*)d_ws;                         // 32 MB
    char* wq2 = (char*)d_ws + (size_t)NDIM * KDIM * 2;                  // 32 MB

    prep_kernel<<<16384 + 2048, 256, 0, stream>>>(x, w, xb, wq2);
    gemm256<<<(MDIM / BM) * (NDIM / BN), 512, 0, stream>>>(xb, wq2, b, out);
}

// Round 14
// 149.935 us; speedup vs baseline: 1.0898x; 1.0898x over previous
//
#include <hip/hip_runtime.h>
#include <hip/hip_bf16.h>
#include <stdint.h>

#define KDIM 4096
#define NDIM 4096
#define MDIM 4096
#define BM 256
#define BN 256
#define BK 64

typedef __attribute__((ext_vector_type(8))) short bf16x8;
typedef __attribute__((ext_vector_type(4))) float f32x4;

// ---------- helpers ----------

__device__ __forceinline__ unsigned short bf16bits(float f) {
    union { float f; uint32_t u; } c; c.f = f;
    uint32_t u = c.u;
    uint32_t r = (u + 0x7fffu + ((u >> 16) & 1u)) >> 16;   // RNE
    return (unsigned short)r;
}

// Faithful FP4 E2M1 quant-dequant (matches reference float math).
__device__ __forceinline__ float fp4qd(float x) {
    float a = fabsf(x);
    if (a == 0.0f) return 0.0f;
    float e = floorf(log2f(a));
    float val;
    if (e < 0.0f) {                       // subnormal path
        float mant = fminf(fmaxf(rintf(a * 2.0f), 0.0f), 1.0f);
        val = mant * 0.5f;
    } else {
        float ec = fminf(e, 2.0f);
        float p  = exp2f(ec);             // exact: 1,2,4
        float mant = fminf(fmaxf(rintf((a / p - 1.0f) * 2.0f), 0.0f), 1.0f);
        val = (1.0f + 0.5f * mant) * p;
    }
    return (x < 0.0f) ? -val : val;
}

__device__ __forceinline__ void gld16(void* lds, const void* g) {
    __builtin_amdgcn_global_load_lds(
        (const __attribute__((address_space(1))) unsigned int*)g,
        (__attribute__((address_space(3))) unsigned int*)lds,
        16, 0, 0);
}

// ---------- fused prep: x f32->bf16  +  weight fp4-quant-dequant->bf16 ----
__global__ __launch_bounds__(256) void prep_kernel(const float* __restrict__ X,
                                                   const float* __restrict__ W,
                                                   unsigned short* __restrict__ Xb,
                                                   unsigned short* __restrict__ Wq) {
    int bid = blockIdx.x;
    int tid = threadIdx.x;
    if (bid < 16384) {
        size_t i = ((size_t)bid * 256 + tid) * 4;
        float4 v = *(const float4*)(X + i);
        ushort4 o;
        o.x = bf16bits(v.x); o.y = bf16bits(v.y);
        o.z = bf16bits(v.z); o.w = bf16bits(v.w);
        *(ushort4*)(Xb + i) = o;
    } else {
        size_t base = ((size_t)(bid - 16384) * 256 + tid) * 4;
        float4 v = *(const float4*)(W + base);
        float am = fmaxf(fmaxf(fabsf(v.x), fabsf(v.y)),
                         fmaxf(fabsf(v.z), fabsf(v.w)));
        #pragma unroll
        for (int s = 16; s; s >>= 1) am = fmaxf(am, __shfl_xor(am, s));  // 32-lane group
        float scale = (am == 0.0f) ? 1.0f : am / 6.0f;
        ushort4 o;
        o.x = bf16bits(fp4qd(v.x / scale) * scale);
        o.y = bf16bits(fp4qd(v.y / scale) * scale);
        o.z = bf16bits(fp4qd(v.z / scale) * scale);
        o.w = bf16bits(fp4qd(v.w / scale) * scale);
        *(ushort4*)(Wq + base) = o;
    }
}

// ---------- GEMM: 256x256-tile, ONE barrier per K-tile, post-MFMA reads ---
// C = A @ B^T + bias. 8 waves (2M x 4N), per-wave 128x64, acc[8][4].
// LDS: smem[buf][op][half][16KB], 128 KiB dbuf. Chunk-XOR swizzle
// (slot = kc ^ (row&7)); conflict-free ds_read_b128.
// K-tile body (buf b; stages & tail-reads target b^1):
//   STAGE x4 (b^1, ktNext)                      // 8 gld16
//   LGKM(8)  -> bvA,bvB,avE serviced (avO outstanding)
//   G1: mh0 x all-n, 32 MFMA                    // reads were issued behind
//   LGKM(0)  -> avO serviced                    //   prev tile's G2 -> hidden
//   VM0      -> own stages drained (slack ~= G1 window)
//   BAR      -> all waves' stages landed; also: any wave here implies all
//               waves' reads of b^1 serviced (they lgkm(0) before their BAR)
//   G2: mh1 x all-n, 32 MFMA
//   READS(b^1): bvA,bvB,avE,avO (24 ds_reads)   // issue behind G2's MFMAs;
//                                               //   serviced under MFMA exec
// WAR (stage vs prior reads): via BAR(t-1) argument above. RAW (read vs
// stage): VM0+BAR precede the tail reads. Register WAR (reads overwrite
// G2 operands): compiler renames/interlocks (SSA).

#define BAR()    __builtin_amdgcn_s_barrier()
#define LGKM(n)  asm volatile("s_waitcnt lgkmcnt(" #n ")" ::: "memory")
#define VM0()    asm volatile("s_waitcnt vmcnt(0)" ::: "memory")
#define SCH0()   __builtin_amdgcn_sched_barrier(0)
#define PRIO(x)  __builtin_amdgcn_s_setprio(x)

__global__ __launch_bounds__(512, 2) void gemm256(const unsigned short* __restrict__ A,
                                                  const unsigned short* __restrict__ B,
                                                  const float* __restrict__ bias,
                                                  float* __restrict__ C) {
    __shared__ __attribute__((aligned(16))) char smem[2][2][2][16384];
    char* sm = (char*)&smem[0][0][0][0];

    const int t = threadIdx.x;
    const int l = t & 63;
    const int w = __builtin_amdgcn_readfirstlane(t >> 6);  // 0..7
    const int wm = w >> 2;        // 0..1  (M half)
    const int wn = w & 3;         // 0..3  (N quarter)

    // bijective XCD swizzle (256 blocks, 8 XCDs)
    int bid = blockIdx.x;
    int swz = (bid & 7) * 32 + (bid >> 3);
    int brow = (swz >> 4) * BM;
    int bcol = (swz & 15) * BN;

    // ---- staging addresses (pre-swizzled global source, linear LDS dest) ----
    const int lr8  = l >> 3;
    const int slot = l & 7;
    const int scol = (slot ^ lr8) << 3;
    const unsigned short* pA = A + (size_t)(brow + w * 8 + lr8) * KDIM + scol;
    const unsigned short* pB = B + (size_t)(bcol + w * 8 + lr8) * KDIM + scol;

#define STAGE(b, op, h, kt) do {                                               \
    const unsigned short* _s = ((op) ? pB : pA)                                \
        + (size_t)(h) * 128 * KDIM + (size_t)(kt) * BK;                        \
    gld16(sm + (b) * 65536 + (op) * 32768 + (h) * 16384 + w * 1024, _s);       \
    gld16(sm + (b) * 65536 + (op) * 32768 + (h) * 16384 + 8192 + w * 1024,     \
          _s + (size_t)64 * KDIM);                                             \
} while (0)

    // ---- fragment read addressing ----
    const int fr  = l & 15;
    const int fq  = l >> 4;
    const int kx0 = ((fq    ) ^ (fr & 7)) << 4;
    const int kx1 = ((fq + 4) ^ (fr & 7)) << 4;
    const int frA = fr * 128;

#define RD_A(b, mh, arr) do {                                                   \
    const char* _p = sm + (b) * 65536 + wm * 16384 + (mh) * 8192 + frA;         \
    _Pragma("unroll")                                                           \
    for (int m = 0; m < 4; ++m) {                                               \
        arr[m][0] = *(const bf16x8*)(_p + m * 2048 + kx0);                      \
        arr[m][1] = *(const bf16x8*)(_p + m * 2048 + kx1);                      \
    }                                                                           \
} while (0)

#define RD_B(b, nh, arr) do {                                                   \
    const char* _p = sm + (b) * 65536 + 32768 + wn * 8192 + (nh) * 4096 + frA;  \
    _Pragma("unroll")                                                           \
    for (int n = 0; n < 2; ++n) {                                               \
        arr[n][0] = *(const bf16x8*)(_p + n * 2048 + kx0);                      \
        arr[n][1] = *(const bf16x8*)(_p + n * 2048 + kx1);                      \
    }                                                                           \
} while (0)

    // one mh-half x all 4 n-frags x 2 ks = 32 MFMA (ks-outer, indep chains)
#define MMG(mh, AV)                                                             \
    _Pragma("unroll")                                                           \
    for (int ks = 0; ks < 2; ++ks)                                              \
        _Pragma("unroll")                                                       \
        for (int m = 0; m < 4; ++m) {                                           \
            acc[(mh)*4+m][0] = __builtin_amdgcn_mfma_f32_16x16x32_bf16(         \
                AV[m][ks], bvA[0][ks], acc[(mh)*4+m][0], 0, 0, 0);              \
            acc[(mh)*4+m][1] = __builtin_amdgcn_mfma_f32_16x16x32_bf16(         \
                AV[m][ks], bvA[1][ks], acc[(mh)*4+m][1], 0, 0, 0);              \
            acc[(mh)*4+m][2] = __builtin_amdgcn_mfma_f32_16x16x32_bf16(         \
                AV[m][ks], bvB[0][ks], acc[(mh)*4+m][2], 0, 0, 0);              \
            acc[(mh)*4+m][3] = __builtin_amdgcn_mfma_f32_16x16x32_bf16(         \
                AV[m][ks], bvB[1][ks], acc[(mh)*4+m][3], 0, 0, 0);              \
        }

    f32x4 acc[8][4];
    #pragma unroll
    for (int m = 0; m < 8; ++m)
        #pragma unroll
        for (int n = 0; n < 4; ++n)
            acc[m][n] = f32x4{0.f, 0.f, 0.f, 0.f};

    bf16x8 avE[4][2], avO[4][2], bvA[2][2], bvB[2][2];

    // one K-tile: consume buf b; stage ktNext into b^1; tail-read b^1
#define TILE_K(b, ktNext) do {                                                  \
    STAGE((b)^1, 0, 0, ktNext); STAGE((b)^1, 0, 1, ktNext);                     \
    STAGE((b)^1, 1, 0, ktNext); STAGE((b)^1, 1, 1, ktNext);                     \
    LGKM(8); SCH0();                                                            \
    PRIO(1); MMG(0, avE); PRIO(0);                                              \
    LGKM(0); SCH0();                                                            \
    VM0();                                                                      \
    BAR(); SCH0();                                                              \
    PRIO(1); MMG(1, avO); PRIO(0);                                              \
    RD_B((b)^1, 0, bvA); RD_B((b)^1, 1, bvB);                                   \
    RD_A((b)^1, 0, avE); RD_A((b)^1, 1, avO);                                   \
} while (0)

    // ---- prologue: stage tile0 -> buf0; drain; barrier; pre-read tile0 ----
    STAGE(0, 0, 0, 0); STAGE(0, 0, 1, 0); STAGE(0, 1, 0, 0); STAGE(0, 1, 1, 0);
    VM0();
    BAR(); SCH0();
    RD_B(0, 0, bvA); RD_B(0, 1, bvB);
    RD_A(0, 0, avE); RD_A(0, 1, avO);

    // ---- main loop: 64 K-tiles, unrolled x2 for compile-time buf index ----
    for (int it = 0; it < 32; ++it) {
        const int k1 = 2 * it + 1;
        const int k2 = (2 * it + 2) & 63;   // wraps on last iter (never consumed)
        TILE_K(0, k1);
        TILE_K(1, k2);
    }

    // ---- epilogue: C[row][col] = acc + bias[col] ----
    // C/D layout: col = lane&15, row = (lane>>4)*4 + reg
    float bb[4];
    #pragma unroll
    for (int n = 0; n < 4; ++n) bb[n] = bias[bcol + wn * 64 + n * 16 + fr];
    #pragma unroll
    for (int mi = 0; mi < 8; ++mi) {
        #pragma unroll
        for (int q = 0; q < 4; ++q) {
            int row = brow + wm * 128 + mi * 16 + fq * 4 + q;
            float* crow = C + (size_t)row * NDIM + bcol + wn * 64;
            #pragma unroll
            for (int n = 0; n < 4; ++n)
                crow[n * 16 + fr] = acc[mi][n][q] + bb[n];
        }
    }
}

// ---------- launch ----------
extern "C" void kernel_launch(void* const* d_in, const int* in_sizes, int n_in,
                              void* d_out, int out_size, void* d_ws, size_t ws_size,
                              hipStream_t stream) {
    const float* x = (const float*)d_in[0];
    const float* w = (const float*)d_in[1];
    const float* b = (const float*)d_in[2];
    float* out = (float*)d_out;

    unsigned short* xb = (unsigned short*)d_ws;                         // 32 MB
    unsigned short* wq = xb + (size_t)NDIM * KDIM;                      // 32 MB

    prep_kernel<<<32768, 256, 0, stream>>>(x, w, xb, wq);
    gemm256<<<(MDIM / BM) * (NDIM / BN), 512, 0, stream>>>(xb, wq, b, out);
}